// Round 2
// baseline (841.803 us; speedup 1.0000x reference)
//
#include <hip/hip_runtime.h>
#include <cstdint>
#include <cstddef>

// ---------------------------------------------------------------------------
// Mamba3Block on MI355X. B=2, L=4096, D_MODEL=1024, D_INNER=D_STATE=2048,
// DT_RANK=64, D_CONV=4.  M = B*L = 8192 rows everywhere.
// Heavy matmuls: bf16 MFMA 16x16x32, 128x128 tile, BK=64,
// global_load_lds width-16 staging (m97 structure). Scans accumulate fp32.
// Workspace layout is liveness-overlaid to ~224 MB (R1 crash: 352 MB layout
// likely exceeded ws_size -> GPU page fault -> SIGABRT).
// ---------------------------------------------------------------------------

typedef unsigned short u16;                 // bf16 storage (bit pattern)
typedef __bf16 bf16x8 __attribute__((ext_vector_type(8)));
typedef float  f32x4  __attribute__((ext_vector_type(4)));

#define BDIM 256
#define M_ROWS 8192            // B*L
#define LSEQ   4096
#define DI     2048            // d_inner / d_state
#define NCH    32              // scan chunks
#define CLEN   128             // LSEQ / NCH

__device__ __forceinline__ float bf2f(u16 h) {
    return __uint_as_float(((unsigned int)h) << 16);
}
__device__ __forceinline__ u16 f2bf(float f) {
    unsigned int u = __float_as_uint(f);
    u = u + 0x7fffu + ((u >> 16) & 1u);     // RNE
    return (u16)(u >> 16);
}
__device__ __forceinline__ float siluf(float v) { return v / (1.0f + expf(-v)); }

__device__ __forceinline__ void load16_to_lds(const u16* g, u16* l) {
    __builtin_amdgcn_global_load_lds((const __attribute__((address_space(1))) void*)g,
                                     (__attribute__((address_space(3))) void*)l,
                                     16, 0, 0);
}

// ---------------------------------------------------------------------------
// f32 -> bf16 convert (n divisible by 1024)
// ---------------------------------------------------------------------------
__global__ void k_cvt(const float* __restrict__ in, u16* __restrict__ out, int n) {
    int i = (blockIdx.x * BDIM + threadIdx.x) * 4;
    if (i >= n) return;
    float4 v = *reinterpret_cast<const float4*>(in + i);
    ushort2 a = {f2bf(v.x), f2bf(v.y)};
    ushort2 b = {f2bf(v.z), f2bf(v.w)};
    *reinterpret_cast<ushort2*>(out + i)     = a;
    *reinterpret_cast<ushort2*>(out + i + 2) = b;
}

// transpose + convert: out[c*R + r] = in[r*C + c]
__global__ void k_transpose_cvt(const float* __restrict__ in, u16* __restrict__ out,
                                int R, int C) {
    __shared__ float t[32][33];
    int r0 = blockIdx.y * 32, c0 = blockIdx.x * 32;
    int tx = threadIdx.x;
    for (int i = threadIdx.y; i < 32; i += 8)
        t[i][tx] = in[(size_t)(r0 + i) * C + c0 + tx];
    __syncthreads();
    for (int i = threadIdx.y; i < 32; i += 8)
        out[(size_t)(c0 + i) * R + r0 + tx] = f2bf(t[tx][i]);
}

// ---------------------------------------------------------------------------
// GEMM: C[M x N] = A1[M x K1] * W1[N x K1]^T (+ A2[M x K2] * W2[N x K2]^T)
// bf16 in, f32 accumulate.
// MODE 0: store bf16. MODE 1: add bf16 addend, store bf16. MODE 2: store f32.
// MODE 5: log-decay epilogue: store bf16 of -exp(bias2[col])*softplus(v+bias1[col])
// ---------------------------------------------------------------------------
template <int MODE>
__global__ __launch_bounds__(256, 2)
void k_gemm(const u16* __restrict__ A1, const u16* __restrict__ W1, int K1,
            const u16* __restrict__ A2, const u16* __restrict__ W2, int K2,
            int N,
            float* __restrict__ outf, u16* __restrict__ outb,
            const u16* __restrict__ addb,
            const float* __restrict__ bias1, const float* __restrict__ bias2) {
    __shared__ u16 As[128 * 64];
    __shared__ u16 Bs[128 * 64];
    const int tid  = threadIdx.x;
    const int wave = tid >> 6;
    const int lane = tid & 63;
    const int m0 = blockIdx.y * 128;
    const int n0 = blockIdx.x * 128;
    const int wm = (wave >> 1) * 64;
    const int wn = (wave & 1) * 64;
    const int lr = lane & 15;
    const int lq = lane >> 4;

    f32x4 acc[4][4] = {};

    const int nt1 = K1 >> 6;
    const int nt2 = K2 >> 6;
    const int ntot = nt1 + nt2;

    for (int kt = 0; kt < ntot; ++kt) {
        const u16* Ap; const u16* Wp; int ld, k0;
        if (kt < nt1) { Ap = A1; Wp = W1; ld = K1; k0 = kt << 6; }
        else          { Ap = A2; Wp = W2; ld = K2; k0 = (kt - nt1) << 6; }
        #pragma unroll
        for (int i = 0; i < 4; ++i) {
            int chunk = wave * 4 + i;            // 0..15 (wave-uniform)
            int flat  = chunk * 512 + lane * 8;  // element offset in 128x64 tile
            int r = flat >> 6;
            int c = flat & 63;
            load16_to_lds(Ap + (size_t)(m0 + r) * ld + (k0 + c), As + chunk * 512);
            load16_to_lds(Wp + (size_t)(n0 + r) * ld + (k0 + c), Bs + chunk * 512);
        }
        __syncthreads();
        #pragma unroll
        for (int kk = 0; kk < 64; kk += 32) {
            bf16x8 af[4], bfr[4];
            #pragma unroll
            for (int i = 0; i < 4; ++i)
                af[i] = *reinterpret_cast<const bf16x8*>(&As[(wm + i * 16 + lr) * 64 + kk + lq * 8]);
            #pragma unroll
            for (int i = 0; i < 4; ++i)
                bfr[i] = *reinterpret_cast<const bf16x8*>(&Bs[(wn + i * 16 + lr) * 64 + kk + lq * 8]);
            #pragma unroll
            for (int mi = 0; mi < 4; ++mi)
                #pragma unroll
                for (int ni = 0; ni < 4; ++ni)
                    acc[mi][ni] = __builtin_amdgcn_mfma_f32_16x16x32_bf16(
                        af[mi], bfr[ni], acc[mi][ni], 0, 0, 0);
        }
        __syncthreads();
    }

    #pragma unroll
    for (int mi = 0; mi < 4; ++mi) {
        #pragma unroll
        for (int ni = 0; ni < 4; ++ni) {
            #pragma unroll
            for (int j = 0; j < 4; ++j) {
                int row = m0 + wm + mi * 16 + lq * 4 + j;
                int col = n0 + wn + ni * 16 + lr;
                size_t idx = (size_t)row * N + col;
                float v = acc[mi][ni][j];
                if constexpr (MODE == 1) v += bf2f(addb[idx]);
                if constexpr (MODE == 5) {
                    float dlt = v + bias1[col];
                    dlt = (dlt > 15.f) ? dlt : log1pf(expf(dlt));
                    v = -expf(bias2[col]) * dlt;          // log-decay
                }
                if constexpr (MODE == 2) outf[idx] = v;
                else                     outb[idx] = f2bf(v);
            }
        }
    }
}

// ---------------------------------------------------------------------------
// depthwise causal conv (k=4) + bias + SiLU over x[M_ROWS x DI]
// ---------------------------------------------------------------------------
__global__ void k_conv(const u16* __restrict__ x, const float* __restrict__ w,
                       const float* __restrict__ b, u16* __restrict__ out) {
    int idx = blockIdx.x * BDIM + threadIdx.x;   // over M_ROWS*DI
    int d  = idx & (DI - 1);
    int bl = idx >> 11;
    int l  = bl & (LSEQ - 1);
    float4 wv = *reinterpret_cast<const float4*>(w + d * 4);
    float wj[4] = {wv.x, wv.y, wv.z, wv.w};
    float acc = b[d];
    #pragma unroll
    for (int j = 0; j < 4; ++j) {
        int ll = l - 3 + j;
        if (ll >= 0) acc += wj[j] * bf2f(x[(size_t)(bl - 3 + j) * DI + d]);
    }
    out[idx] = f2bf(siluf(acc));
}

// ---------------------------------------------------------------------------
// cumsum over l (3-phase chunked): Bx bf16 -> states bf16 (fp32 accumulate)
// thread layout: t = ((b*NCH + c)*DI + s)
// ---------------------------------------------------------------------------
__global__ void k_cumsum_p1(const u16* __restrict__ Bx, float* __restrict__ aux) {
    int t = blockIdx.x * BDIM + threadIdx.x;
    int s = t & (DI - 1);
    int c = (t >> 11) & (NCH - 1);
    int b = t >> 16;
    const u16* p = Bx + ((size_t)(b * LSEQ + c * CLEN) * DI) + s;
    float sum = 0.f;
    for (int i = 0; i < CLEN; ++i) sum += bf2f(p[(size_t)i * DI]);
    aux[t] = sum;
}
__global__ void k_cumsum_p2(const float* __restrict__ aux, float* __restrict__ carry) {
    int t = blockIdx.x * BDIM + threadIdx.x;   // over B*DI
    int s = t & (DI - 1);
    int b = t >> 11;
    float run = 0.f;
    for (int c = 0; c < NCH; ++c) {
        int i = (b * NCH + c) * DI + s;
        carry[i] = run;
        run += aux[i];
    }
}
__global__ void k_cumsum_p3(const u16* __restrict__ Bx, const float* __restrict__ carry,
                            u16* __restrict__ st) {
    int t = blockIdx.x * BDIM + threadIdx.x;
    int s = t & (DI - 1);
    int c = (t >> 11) & (NCH - 1);
    int b = t >> 16;
    size_t base = ((size_t)(b * LSEQ + c * CLEN) * DI) + s;
    float run = carry[t];
    for (int i = 0; i < CLEN; ++i) {
        run += bf2f(Bx[base + (size_t)i * DI]);
        st[base + (size_t)i * DI] = f2bf(run);
    }
}

// ---------------------------------------------------------------------------
// selective scan (3-phase): s_l = a_l * s_{l-1} + u_l  with a = exp(logdec)
// p3 fuses: x4 = s + u*D_ss ; out = x4 * silu(z)
// ---------------------------------------------------------------------------
__global__ void k_scan_p1(const u16* __restrict__ ld_, const u16* __restrict__ u,
                          float* __restrict__ auxA, float* __restrict__ auxS) {
    int t = blockIdx.x * BDIM + threadIdx.x;
    int d = t & (DI - 1);
    int c = (t >> 11) & (NCH - 1);
    int b = t >> 16;
    size_t base = ((size_t)(b * LSEQ + c * CLEN) * DI) + d;
    float ap = 1.f, s = 0.f;
    for (int i = 0; i < CLEN; ++i) {
        size_t ix = base + (size_t)i * DI;
        float a = expf(bf2f(ld_[ix]));
        s = fmaf(a, s, bf2f(u[ix]));
        ap *= a;
    }
    auxA[t] = ap; auxS[t] = s;
}
__global__ void k_scan_p2(const float* __restrict__ auxA, const float* __restrict__ auxS,
                          float* __restrict__ carry) {
    int t = blockIdx.x * BDIM + threadIdx.x;   // over B*DI
    int d = t & (DI - 1);
    int b = t >> 11;
    float run = 0.f;
    for (int c = 0; c < NCH; ++c) {
        int i = (b * NCH + c) * DI + d;
        carry[i] = run;
        run = fmaf(auxA[i], run, auxS[i]);
    }
}
__global__ void k_scan_p3(const u16* __restrict__ ld_, const u16* __restrict__ u,
                          const float* __restrict__ carry, const u16* __restrict__ z,
                          const float* __restrict__ Dss, u16* __restrict__ outb) {
    int t = blockIdx.x * BDIM + threadIdx.x;
    int d = t & (DI - 1);
    int c = (t >> 11) & (NCH - 1);
    int b = t >> 16;
    size_t base = ((size_t)(b * LSEQ + c * CLEN) * DI) + d;
    float s = carry[t];
    float dss = Dss[d];
    for (int i = 0; i < CLEN; ++i) {
        size_t ix = base + (size_t)i * DI;
        float a = expf(bf2f(ld_[ix]));
        float uu = bf2f(u[ix]);
        s = fmaf(a, s, uu);
        float x4 = s + uu * dss;
        float zz = bf2f(z[ix]);
        outb[ix] = f2bf(x4 * siluf(zz));
    }
}

// ---------------------------------------------------------------------------
extern "C" void kernel_launch(void* const* d_in, const int* in_sizes, int n_in,
                              void* d_out, int out_size, void* d_ws, size_t ws_size,
                              hipStream_t stream) {
    const float* hs     = (const float*)d_in[0];
    const float* delta  = (const float*)d_in[1];
    const float* inproj = (const float*)d_in[2];
    const float* convw  = (const float*)d_in[3];
    const float* convb  = (const float*)d_in[4];
    const float* Areal  = (const float*)d_in[5];
    const float* Bw     = (const float*)d_in[6];
    const float* Cw     = (const float*)d_in[7];
    const float* Dw     = (const float*)d_in[8];
    const float* dtw    = (const float*)d_in[9];
    const float* dtb    = (const float*)d_in[10];
    const float* Alog   = (const float*)d_in[11];
    const float* Dss    = (const float*)d_in[12];
    const float* outw   = (const float*)d_in[13];
    float* out = (float*)d_out;

    // ---- liveness-overlaid workspace layout (~224 MB total) ----
    const size_t SZ_ACT = (size_t)M_ROWS * DI * 2;     // 32 MB
    char* p = (char*)d_ws;
    u16* ZB  = (u16*)p; p += SZ_ACT;                   // z: G1 -> scan_p3
    u16* XB  = (u16*)p;                                // x: G1 -> conv
    u16* X3  = XB;      p += SZ_ACT;                   // X3: G45 -> scan_p3
    u16* XC  = (u16*)p;                                // conv out: -> G2
    u16* ST  = XC;      p += SZ_ACT;                   // states: cumsum_p3 -> G45
    u16* X2  = (u16*)p;                                // G2 out: -> G45
    u16* OUT = X2;      p += SZ_ACT;                   // scan_p3 out: -> G7
    u16* BX  = (u16*)p;                                // G3 out: -> cumsum_p3
    u16* LD  = BX;      p += SZ_ACT;                   // log-decay: G6 -> scan_p3
    u16* XH  = (u16*)p; p += (size_t)M_ROWS * 1024 * 2;   // 16 MB
    u16* W1  = (u16*)p; p += (size_t)4096 * 1024 * 2;     // 8 MB
    u16* WA  = (u16*)p; p += (size_t)DI * DI * 2;         // 8 MB
    u16* WB  = (u16*)p; p += (size_t)DI * DI * 2;
    u16* WC  = (u16*)p; p += (size_t)DI * DI * 2;
    u16* WD  = (u16*)p; p += (size_t)DI * DI * 2;
    u16* WO  = (u16*)p; p += (size_t)1024 * DI * 2;       // 4 MB
    u16* WDT = (u16*)p; p += (size_t)DI * 64 * 2;
    u16* DLT = (u16*)p; p += (size_t)M_ROWS * 64 * 2;
    float* aux1 = (float*)p; p += (size_t)2 * NCH * DI * 4;
    float* aux2 = (float*)p; p += (size_t)2 * NCH * DI * 4;
    float* auxA = (float*)p; p += (size_t)2 * NCH * DI * 4;
    float* auxS = (float*)p; p += (size_t)2 * NCH * DI * 4;
    float* auxC = (float*)p; p += (size_t)2 * NCH * DI * 4;

    // ---- weight / activation converts ----
    k_cvt<<<8192, BDIM, 0, stream>>>(hs,    XH,  M_ROWS * 1024);
    k_cvt<<<512,  BDIM, 0, stream>>>(delta, DLT, M_ROWS * 64);
    k_cvt<<<4096, BDIM, 0, stream>>>(inproj, W1, 4096 * 1024);
    k_cvt<<<4096, BDIM, 0, stream>>>(Bw,    WB,  DI * DI);
    k_cvt<<<4096, BDIM, 0, stream>>>(Cw,    WC,  DI * DI);
    k_cvt<<<4096, BDIM, 0, stream>>>(Dw,    WD,  DI * DI);
    k_cvt<<<2048, BDIM, 0, stream>>>(outw,  WO,  1024 * DI);
    k_cvt<<<128,  BDIM, 0, stream>>>(dtw,   WDT, DI * 64);
    k_transpose_cvt<<<dim3(64, 64), dim3(32, 8), 0, stream>>>(Areal, WA, DI, DI);

    // ---- G1: x = hs @ in_proj[0:2048]^T ; z = hs @ in_proj[2048:4096]^T ----
    k_gemm<0><<<dim3(16, 64), BDIM, 0, stream>>>(XH, W1, 1024, nullptr, nullptr, 0,
                                                 DI, nullptr, XB, nullptr, nullptr, nullptr);
    k_gemm<0><<<dim3(16, 64), BDIM, 0, stream>>>(XH, W1 + (size_t)DI * 1024, 1024,
                                                 nullptr, nullptr, 0,
                                                 DI, nullptr, ZB, nullptr, nullptr, nullptr);
    // ---- conv + SiLU ----
    k_conv<<<(M_ROWS * DI) / BDIM, BDIM, 0, stream>>>(XB, convw, convb, XC);
    // ---- G2: X2 = XC @ A_real (as WA^T) + XC ----
    k_gemm<1><<<dim3(16, 64), BDIM, 0, stream>>>(XC, WA, DI, nullptr, nullptr, 0,
                                                 DI, nullptr, X2, XC, nullptr, nullptr);
    // ---- G3: BX = X2 @ B_w^T (bf16 out) ----
    k_gemm<0><<<dim3(16, 64), BDIM, 0, stream>>>(X2, WB, DI, nullptr, nullptr, 0,
                                                 DI, nullptr, BX, nullptr, nullptr, nullptr);
    // ---- cumsum -> states (bf16, into XC region) ----
    k_cumsum_p1<<<(2 * NCH * DI) / BDIM, BDIM, 0, stream>>>(BX, aux1);
    k_cumsum_p2<<<(2 * DI) / BDIM, BDIM, 0, stream>>>(aux1, aux2);
    k_cumsum_p3<<<(2 * NCH * DI) / BDIM, BDIM, 0, stream>>>(BX, aux2, ST);
    // ---- G6: LD = -exp(A_log) * softplus(delta @ dt_proj^T + dt_b)  (after cumsum: LD overlays BX) ----
    k_gemm<5><<<dim3(16, 64), BDIM, 0, stream>>>(DLT, WDT, 64, nullptr, nullptr, 0,
                                                 DI, nullptr, LD, nullptr, dtb, Alog);
    // ---- G45: X3 = ST@C_w^T + X2@D_w^T + X2  (X3 overlays dead XB) ----
    k_gemm<1><<<dim3(16, 64), BDIM, 0, stream>>>(ST, WC, DI, X2, WD, DI,
                                                 DI, nullptr, X3, X2, nullptr, nullptr);
    // ---- selective scan + fused epilogue -> OUT (overlays dead X2) ----
    k_scan_p1<<<(2 * NCH * DI) / BDIM, BDIM, 0, stream>>>(LD, X3, auxA, auxS);
    k_scan_p2<<<(2 * DI) / BDIM, BDIM, 0, stream>>>(auxA, auxS, auxC);
    k_scan_p3<<<(2 * NCH * DI) / BDIM, BDIM, 0, stream>>>(LD, X3, auxC, ZB, Dss, OUT);
    // ---- G7: out = OUT @ out_proj^T (M=8192, N=1024, K=2048, f32 out) ----
    k_gemm<2><<<dim3(8, 64), BDIM, 0, stream>>>(OUT, WO, DI, nullptr, nullptr, 0,
                                                1024, out, nullptr, nullptr, nullptr, nullptr);
}

// Round 3
// 784.131 us; speedup vs baseline: 1.0735x; 1.0735x over previous
//
#include <hip/hip_runtime.h>
#include <cstdint>
#include <cstddef>

// ---------------------------------------------------------------------------
// Mamba3Block on MI355X. B=2, L=4096, D_MODEL=1024, D_INNER=D_STATE=2048,
// DT_RANK=64, D_CONV=4.  M = B*L = 8192 rows everywhere.
// Heavy matmuls: bf16 MFMA 16x16x32, 128x128 tile, BK=64,
// global_load_lds width-16 staging. R3: XOR-swizzled LDS layout
// (element (r,c) at r*64 + (c ^ ((r&7)*8))) to kill the 16-way bank
// conflicts measured in R2 (SQ_LDS_BANK_CONFLICT=5e7/dispatch).
// Scans accumulate fp32; decay stored as bf16 LOG-decay (conditioning).
// ---------------------------------------------------------------------------

typedef unsigned short u16;                 // bf16 storage (bit pattern)
typedef __bf16 bf16x8 __attribute__((ext_vector_type(8)));
typedef float  f32x4  __attribute__((ext_vector_type(4)));

#define BDIM 256
#define M_ROWS 8192            // B*L
#define LSEQ   4096
#define DI     2048            // d_inner / d_state
#define NCH    64              // scan chunks (R3: 32->64 for occupancy)
#define CLEN   64              // LSEQ / NCH

__device__ __forceinline__ float bf2f(u16 h) {
    return __uint_as_float(((unsigned int)h) << 16);
}
__device__ __forceinline__ u16 f2bf(float f) {
    unsigned int u = __float_as_uint(f);
    u = u + 0x7fffu + ((u >> 16) & 1u);     // RNE
    return (u16)(u >> 16);
}
__device__ __forceinline__ float siluf(float v) { return v / (1.0f + expf(-v)); }

__device__ __forceinline__ void load16_to_lds(const u16* g, u16* l) {
    __builtin_amdgcn_global_load_lds((const __attribute__((address_space(1))) void*)g,
                                     (__attribute__((address_space(3))) void*)l,
                                     16, 0, 0);
}

// ---------------------------------------------------------------------------
// f32 -> bf16 convert (n divisible by 1024)
// ---------------------------------------------------------------------------
__global__ void k_cvt(const float* __restrict__ in, u16* __restrict__ out, int n) {
    int i = (blockIdx.x * BDIM + threadIdx.x) * 4;
    if (i >= n) return;
    float4 v = *reinterpret_cast<const float4*>(in + i);
    ushort2 a = {f2bf(v.x), f2bf(v.y)};
    ushort2 b = {f2bf(v.z), f2bf(v.w)};
    *reinterpret_cast<ushort2*>(out + i)     = a;
    *reinterpret_cast<ushort2*>(out + i + 2) = b;
}

// transpose + convert: out[c*R + r] = in[r*C + c]
__global__ void k_transpose_cvt(const float* __restrict__ in, u16* __restrict__ out,
                                int R, int C) {
    __shared__ float t[32][33];
    int r0 = blockIdx.y * 32, c0 = blockIdx.x * 32;
    int tx = threadIdx.x;
    for (int i = threadIdx.y; i < 32; i += 8)
        t[i][tx] = in[(size_t)(r0 + i) * C + c0 + tx];
    __syncthreads();
    for (int i = threadIdx.y; i < 32; i += 8)
        out[(size_t)(c0 + i) * R + r0 + tx] = f2bf(t[tx][i]);
}

// ---------------------------------------------------------------------------
// GEMM: C[M x N] = A1[M x K1] * W1[N x K1]^T (+ A2[M x K2] * W2[N x K2]^T)
// bf16 in, f32 accumulate. LDS tiles XOR-swizzled: (r,c) -> r*64 + (c^((r&7)*8)).
// MODE 0: store bf16. MODE 1: add bf16 addend, store bf16. MODE 2: store f32.
// MODE 5: log-decay epilogue: store bf16 of -exp(bias2[col])*softplus(v+bias1[col])
// ---------------------------------------------------------------------------
template <int MODE>
__global__ __launch_bounds__(256, 2)
void k_gemm(const u16* __restrict__ A1, const u16* __restrict__ W1, int K1,
            const u16* __restrict__ A2, const u16* __restrict__ W2, int K2,
            int N,
            float* __restrict__ outf, u16* __restrict__ outb,
            const u16* __restrict__ addb,
            const float* __restrict__ bias1, const float* __restrict__ bias2) {
    __shared__ u16 As[128 * 64];
    __shared__ u16 Bs[128 * 64];
    const int tid  = threadIdx.x;
    const int wave = tid >> 6;
    const int lane = tid & 63;
    const int m0 = blockIdx.y * 128;
    const int n0 = blockIdx.x * 128;
    const int wm = (wave >> 1) * 64;
    const int wn = (wave & 1) * 64;
    const int lr = lane & 15;
    const int lq = lane >> 4;
    // staging: lane L of chunk ch fills LDS flat [ch*512 + L*8 .. +7], i.e.
    // row r = ch*8 + (L>>3); swizzled col c = ((L&7) ^ (L>>3)) * 8
    const int stg_row = lane >> 3;                    // row within chunk (0..7)
    const int stg_col = (((lane & 7) ^ (lane >> 3)) << 3);

    f32x4 acc[4][4] = {};

    const int nt1 = K1 >> 6;
    const int nt2 = K2 >> 6;
    const int ntot = nt1 + nt2;

    for (int kt = 0; kt < ntot; ++kt) {
        const u16* Ap; const u16* Wp; int ld, k0;
        if (kt < nt1) { Ap = A1; Wp = W1; ld = K1; k0 = kt << 6; }
        else          { Ap = A2; Wp = W2; ld = K2; k0 = (kt - nt1) << 6; }
        #pragma unroll
        for (int i = 0; i < 4; ++i) {
            int chunk = wave * 4 + i;                 // 0..15 (wave-uniform)
            int r = chunk * 8 + stg_row;              // tile row this lane feeds
            load16_to_lds(Ap + (size_t)(m0 + r) * ld + (k0 + stg_col), As + chunk * 512);
            load16_to_lds(Wp + (size_t)(n0 + r) * ld + (k0 + stg_col), Bs + chunk * 512);
        }
        __syncthreads();
        #pragma unroll
        for (int kk = 0; kk < 64; kk += 32) {
            bf16x8 af[4], bfr[4];
            #pragma unroll
            for (int i = 0; i < 4; ++i) {
                int R = wm + i * 16 + lr;
                af[i] = *reinterpret_cast<const bf16x8*>(
                    &As[R * 64 + ((kk + lq * 8) ^ ((R & 7) << 3))]);
            }
            #pragma unroll
            for (int i = 0; i < 4; ++i) {
                int R = wn + i * 16 + lr;
                bfr[i] = *reinterpret_cast<const bf16x8*>(
                    &Bs[R * 64 + ((kk + lq * 8) ^ ((R & 7) << 3))]);
            }
            #pragma unroll
            for (int mi = 0; mi < 4; ++mi)
                #pragma unroll
                for (int ni = 0; ni < 4; ++ni)
                    acc[mi][ni] = __builtin_amdgcn_mfma_f32_16x16x32_bf16(
                        af[mi], bfr[ni], acc[mi][ni], 0, 0, 0);
        }
        __syncthreads();
    }

    #pragma unroll
    for (int mi = 0; mi < 4; ++mi) {
        #pragma unroll
        for (int ni = 0; ni < 4; ++ni) {
            #pragma unroll
            for (int j = 0; j < 4; ++j) {
                int row = m0 + wm + mi * 16 + lq * 4 + j;
                int col = n0 + wn + ni * 16 + lr;
                size_t idx = (size_t)row * N + col;
                float v = acc[mi][ni][j];
                if constexpr (MODE == 1) v += bf2f(addb[idx]);
                if constexpr (MODE == 5) {
                    float dlt = v + bias1[col];
                    dlt = (dlt > 15.f) ? dlt : log1pf(expf(dlt));
                    v = -expf(bias2[col]) * dlt;          // log-decay
                }
                if constexpr (MODE == 2) outf[idx] = v;
                else                     outb[idx] = f2bf(v);
            }
        }
    }
}

// ---------------------------------------------------------------------------
// depthwise causal conv (k=4) + bias + SiLU over x[M_ROWS x DI]
// ---------------------------------------------------------------------------
__global__ void k_conv(const u16* __restrict__ x, const float* __restrict__ w,
                       const float* __restrict__ b, u16* __restrict__ out) {
    int idx = blockIdx.x * BDIM + threadIdx.x;   // over M_ROWS*DI
    int d  = idx & (DI - 1);
    int bl = idx >> 11;
    int l  = bl & (LSEQ - 1);
    float4 wv = *reinterpret_cast<const float4*>(w + d * 4);
    float wj[4] = {wv.x, wv.y, wv.z, wv.w};
    float acc = b[d];
    #pragma unroll
    for (int j = 0; j < 4; ++j) {
        int ll = l - 3 + j;
        if (ll >= 0) acc += wj[j] * bf2f(x[(size_t)(bl - 3 + j) * DI + d]);
    }
    out[idx] = f2bf(siluf(acc));
}

// ---------------------------------------------------------------------------
// cumsum over l (3-phase chunked): Bx bf16 -> states bf16 (fp32 accumulate)
// thread layout: t = ((b*NCH + c)*DI + s)
// ---------------------------------------------------------------------------
__global__ void k_cumsum_p1(const u16* __restrict__ Bx, float* __restrict__ aux) {
    int t = blockIdx.x * BDIM + threadIdx.x;
    int s = t & (DI - 1);
    int c = (t >> 11) & (NCH - 1);
    int b = t >> 17;
    const u16* p = Bx + ((size_t)(b * LSEQ + c * CLEN) * DI) + s;
    float sum = 0.f;
    for (int i = 0; i < CLEN; ++i) sum += bf2f(p[(size_t)i * DI]);
    aux[t] = sum;
}
__global__ void k_cumsum_p2(const float* __restrict__ aux, float* __restrict__ carry) {
    int t = blockIdx.x * BDIM + threadIdx.x;   // over B*DI
    int s = t & (DI - 1);
    int b = t >> 11;
    float run = 0.f;
    for (int c = 0; c < NCH; ++c) {
        int i = (b * NCH + c) * DI + s;
        carry[i] = run;
        run += aux[i];
    }
}
__global__ void k_cumsum_p3(const u16* __restrict__ Bx, const float* __restrict__ carry,
                            u16* __restrict__ st) {
    int t = blockIdx.x * BDIM + threadIdx.x;
    int s = t & (DI - 1);
    int c = (t >> 11) & (NCH - 1);
    int b = t >> 17;
    size_t base = ((size_t)(b * LSEQ + c * CLEN) * DI) + s;
    float run = carry[t];
    for (int i = 0; i < CLEN; ++i) {
        run += bf2f(Bx[base + (size_t)i * DI]);
        st[base + (size_t)i * DI] = f2bf(run);
    }
}

// ---------------------------------------------------------------------------
// selective scan (3-phase): s_l = a_l * s_{l-1} + u_l  with a = exp(logdec)
// p3 fuses: x4 = s + u*D_ss ; out = x4 * silu(z)
// ---------------------------------------------------------------------------
__global__ void k_scan_p1(const u16* __restrict__ ld_, const u16* __restrict__ u,
                          float* __restrict__ auxA, float* __restrict__ auxS) {
    int t = blockIdx.x * BDIM + threadIdx.x;
    int d = t & (DI - 1);
    int c = (t >> 11) & (NCH - 1);
    int b = t >> 17;
    size_t base = ((size_t)(b * LSEQ + c * CLEN) * DI) + d;
    float ap = 1.f, s = 0.f;
    for (int i = 0; i < CLEN; ++i) {
        size_t ix = base + (size_t)i * DI;
        float a = expf(bf2f(ld_[ix]));
        s = fmaf(a, s, bf2f(u[ix]));
        ap *= a;
    }
    auxA[t] = ap; auxS[t] = s;
}
__global__ void k_scan_p2(const float* __restrict__ auxA, const float* __restrict__ auxS,
                          float* __restrict__ carry) {
    int t = blockIdx.x * BDIM + threadIdx.x;   // over B*DI
    int d = t & (DI - 1);
    int b = t >> 11;
    float run = 0.f;
    for (int c = 0; c < NCH; ++c) {
        int i = (b * NCH + c) * DI + d;
        carry[i] = run;
        run = fmaf(auxA[i], run, auxS[i]);
    }
}
__global__ void k_scan_p3(const u16* __restrict__ ld_, const u16* __restrict__ u,
                          const float* __restrict__ carry, const u16* __restrict__ z,
                          const float* __restrict__ Dss, u16* __restrict__ outb) {
    int t = blockIdx.x * BDIM + threadIdx.x;
    int d = t & (DI - 1);
    int c = (t >> 11) & (NCH - 1);
    int b = t >> 17;
    size_t base = ((size_t)(b * LSEQ + c * CLEN) * DI) + d;
    float s = carry[t];
    float dss = Dss[d];
    for (int i = 0; i < CLEN; ++i) {
        size_t ix = base + (size_t)i * DI;
        float a = expf(bf2f(ld_[ix]));
        float uu = bf2f(u[ix]);
        s = fmaf(a, s, uu);
        float x4 = s + uu * dss;
        float zz = bf2f(z[ix]);
        outb[ix] = f2bf(x4 * siluf(zz));
    }
}

// ---------------------------------------------------------------------------
extern "C" void kernel_launch(void* const* d_in, const int* in_sizes, int n_in,
                              void* d_out, int out_size, void* d_ws, size_t ws_size,
                              hipStream_t stream) {
    const float* hs     = (const float*)d_in[0];
    const float* delta  = (const float*)d_in[1];
    const float* inproj = (const float*)d_in[2];
    const float* convw  = (const float*)d_in[3];
    const float* convb  = (const float*)d_in[4];
    const float* Areal  = (const float*)d_in[5];
    const float* Bw     = (const float*)d_in[6];
    const float* Cw     = (const float*)d_in[7];
    const float* Dw     = (const float*)d_in[8];
    const float* dtw    = (const float*)d_in[9];
    const float* dtb    = (const float*)d_in[10];
    const float* Alog   = (const float*)d_in[11];
    const float* Dss    = (const float*)d_in[12];
    const float* outw   = (const float*)d_in[13];
    float* out = (float*)d_out;

    // ---- liveness-overlaid workspace layout (~224 MB total) ----
    const size_t SZ_ACT = (size_t)M_ROWS * DI * 2;     // 32 MB
    char* p = (char*)d_ws;
    u16* ZB  = (u16*)p; p += SZ_ACT;                   // z: G1 -> scan_p3
    u16* XB  = (u16*)p;                                // x: G1 -> conv
    u16* X3  = XB;      p += SZ_ACT;                   // X3: G45 -> scan_p3
    u16* XC  = (u16*)p;                                // conv out: -> G2
    u16* ST  = XC;      p += SZ_ACT;                   // states: cumsum_p3 -> G45
    u16* X2  = (u16*)p;                                // G2 out: -> G45
    u16* OUT = X2;      p += SZ_ACT;                   // scan_p3 out: -> G7
    u16* BX  = (u16*)p;                                // G3 out: -> cumsum_p3
    u16* LD  = BX;      p += SZ_ACT;                   // log-decay: G6 -> scan_p3
    u16* XH  = (u16*)p; p += (size_t)M_ROWS * 1024 * 2;   // 16 MB
    u16* W1  = (u16*)p; p += (size_t)4096 * 1024 * 2;     // 8 MB
    u16* WA  = (u16*)p; p += (size_t)DI * DI * 2;         // 8 MB
    u16* WB  = (u16*)p; p += (size_t)DI * DI * 2;
    u16* WC  = (u16*)p; p += (size_t)DI * DI * 2;
    u16* WD  = (u16*)p; p += (size_t)DI * DI * 2;
    u16* WO  = (u16*)p; p += (size_t)1024 * DI * 2;       // 4 MB
    u16* WDT = (u16*)p; p += (size_t)DI * 64 * 2;
    u16* DLT = (u16*)p; p += (size_t)M_ROWS * 64 * 2;
    float* aux1 = (float*)p; p += (size_t)2 * NCH * DI * 4;
    float* aux2 = (float*)p; p += (size_t)2 * NCH * DI * 4;
    float* auxA = (float*)p; p += (size_t)2 * NCH * DI * 4;
    float* auxS = (float*)p; p += (size_t)2 * NCH * DI * 4;
    float* auxC = (float*)p; p += (size_t)2 * NCH * DI * 4;

    // ---- weight / activation converts ----
    k_cvt<<<8192, BDIM, 0, stream>>>(hs,    XH,  M_ROWS * 1024);
    k_cvt<<<512,  BDIM, 0, stream>>>(delta, DLT, M_ROWS * 64);
    k_cvt<<<4096, BDIM, 0, stream>>>(inproj, W1, 4096 * 1024);
    k_cvt<<<4096, BDIM, 0, stream>>>(Bw,    WB,  DI * DI);
    k_cvt<<<4096, BDIM, 0, stream>>>(Cw,    WC,  DI * DI);
    k_cvt<<<4096, BDIM, 0, stream>>>(Dw,    WD,  DI * DI);
    k_cvt<<<2048, BDIM, 0, stream>>>(outw,  WO,  1024 * DI);
    k_cvt<<<128,  BDIM, 0, stream>>>(dtw,   WDT, DI * 64);
    k_transpose_cvt<<<dim3(64, 64), dim3(32, 8), 0, stream>>>(Areal, WA, DI, DI);

    // ---- G1: x = hs @ in_proj[0:2048]^T ; z = hs @ in_proj[2048:4096]^T ----
    k_gemm<0><<<dim3(16, 64), BDIM, 0, stream>>>(XH, W1, 1024, nullptr, nullptr, 0,
                                                 DI, nullptr, XB, nullptr, nullptr, nullptr);
    k_gemm<0><<<dim3(16, 64), BDIM, 0, stream>>>(XH, W1 + (size_t)DI * 1024, 1024,
                                                 nullptr, nullptr, 0,
                                                 DI, nullptr, ZB, nullptr, nullptr, nullptr);
    // ---- conv + SiLU ----
    k_conv<<<(M_ROWS * DI) / BDIM, BDIM, 0, stream>>>(XB, convw, convb, XC);
    // ---- G2: X2 = XC @ A_real (as WA^T) + XC ----
    k_gemm<1><<<dim3(16, 64), BDIM, 0, stream>>>(XC, WA, DI, nullptr, nullptr, 0,
                                                 DI, nullptr, X2, XC, nullptr, nullptr);
    // ---- G3: BX = X2 @ B_w^T (bf16 out) ----
    k_gemm<0><<<dim3(16, 64), BDIM, 0, stream>>>(X2, WB, DI, nullptr, nullptr, 0,
                                                 DI, nullptr, BX, nullptr, nullptr, nullptr);
    // ---- cumsum -> states (bf16, into XC region) ----
    k_cumsum_p1<<<(2 * NCH * DI) / BDIM, BDIM, 0, stream>>>(BX, aux1);
    k_cumsum_p2<<<(2 * DI) / BDIM, BDIM, 0, stream>>>(aux1, aux2);
    k_cumsum_p3<<<(2 * NCH * DI) / BDIM, BDIM, 0, stream>>>(BX, aux2, ST);
    // ---- G6: LD = -exp(A_log) * softplus(delta @ dt_proj^T + dt_b) ----
    k_gemm<5><<<dim3(16, 64), BDIM, 0, stream>>>(DLT, WDT, 64, nullptr, nullptr, 0,
                                                 DI, nullptr, LD, nullptr, dtb, Alog);
    // ---- G45: X3 = ST@C_w^T + X2@D_w^T + X2  (X3 overlays dead XB) ----
    k_gemm<1><<<dim3(16, 64), BDIM, 0, stream>>>(ST, WC, DI, X2, WD, DI,
                                                 DI, nullptr, X3, X2, nullptr, nullptr);
    // ---- selective scan + fused epilogue -> OUT (overlays dead X2) ----
    k_scan_p1<<<(2 * NCH * DI) / BDIM, BDIM, 0, stream>>>(LD, X3, auxA, auxS);
    k_scan_p2<<<(2 * DI) / BDIM, BDIM, 0, stream>>>(auxA, auxS, auxC);
    k_scan_p3<<<(2 * NCH * DI) / BDIM, BDIM, 0, stream>>>(LD, X3, auxC, ZB, Dss, OUT);
    // ---- G7: out = OUT @ out_proj^T (M=8192, N=1024, K=2048, f32 out) ----
    k_gemm<2><<<dim3(8, 64), BDIM, 0, stream>>>(OUT, WO, DI, nullptr, nullptr, 0,
                                                1024, out, nullptr, nullptr, nullptr, nullptr);
}

// Round 5
// 743.304 us; speedup vs baseline: 1.1325x; 1.0549x over previous
//
#include <hip/hip_runtime.h>
#include <cstdint>
#include <cstddef>

// ---------------------------------------------------------------------------
// Mamba3Block on MI355X. B=2, L=4096, D_MODEL=1024, D_INNER=D_STATE=2048.
// R4/R5: algebraic folding P=I+A_real: G2 eliminated;
//   WB' = B_w @ P^T, WX' = (I+D_w) @ P^T  (precomputed 2048^3 GEMMs)
//   BX  = XC @ WB'^T ;  X3 = ST @ C_w^T + XC @ WX'^T
// GEMM: bf16 MFMA 16x16x32, 128x128 tile, BK=64, global_load_lds width-16,
// XOR-swizzled LDS (R3: conflicts 5e7 -> 0), XCD-aware block swizzle,
// __launch_bounds__(256,4). Scans fp32 with bf16 log-decay storage.
// R5 fixes R4's compile error (G7 call was missing one nullptr arg).
// ---------------------------------------------------------------------------

typedef unsigned short u16;                 // bf16 storage (bit pattern)
typedef __bf16 bf16x8 __attribute__((ext_vector_type(8)));
typedef float  f32x4  __attribute__((ext_vector_type(4)));

#define BDIM 256
#define M_ROWS 8192            // B*L
#define LSEQ   4096
#define DI     2048            // d_inner / d_state
#define NCH    64              // scan chunks
#define CLEN   64              // LSEQ / NCH

__device__ __forceinline__ float bf2f(u16 h) {
    return __uint_as_float(((unsigned int)h) << 16);
}
__device__ __forceinline__ u16 f2bf(float f) {
    unsigned int u = __float_as_uint(f);
    u = u + 0x7fffu + ((u >> 16) & 1u);     // RNE
    return (u16)(u >> 16);
}
__device__ __forceinline__ float siluf(float v) { return v / (1.0f + expf(-v)); }

__device__ __forceinline__ void load16_to_lds(const u16* g, u16* l) {
    __builtin_amdgcn_global_load_lds((const __attribute__((address_space(1))) void*)g,
                                     (__attribute__((address_space(3))) void*)l,
                                     16, 0, 0);
}

// ---------------------------------------------------------------------------
// fused f32 -> bf16 convert of all plain weight/activation inputs (1 launch)
// segment element boundaries (all div by 4): hs 8388608 | inproj -> 12582912 |
// Bw -> 16777216 | Cw -> 20971520 | outw -> 23068672 | delta -> 23592960 |
// dtw -> 23724032
// ---------------------------------------------------------------------------
__global__ void k_cvt_all(const float* __restrict__ hs, const float* __restrict__ inproj,
                          const float* __restrict__ Bw, const float* __restrict__ Cw,
                          const float* __restrict__ outw, const float* __restrict__ delta,
                          const float* __restrict__ dtw,
                          u16* __restrict__ XH, u16* __restrict__ W1, u16* __restrict__ WBb,
                          u16* __restrict__ WC, u16* __restrict__ WO, u16* __restrict__ DLT,
                          u16* __restrict__ WDT) {
    long i = (long)(blockIdx.x * BDIM + threadIdx.x) * 4;
    const float* src; u16* dst; long off;
    if      (i <  8388608L) { src = hs;     dst = XH;  off = 0L; }
    else if (i < 12582912L) { src = inproj; dst = W1;  off = 8388608L; }
    else if (i < 16777216L) { src = Bw;     dst = WBb; off = 12582912L; }
    else if (i < 20971520L) { src = Cw;     dst = WC;  off = 16777216L; }
    else if (i < 23068672L) { src = outw;   dst = WO;  off = 20971520L; }
    else if (i < 23592960L) { src = delta;  dst = DLT; off = 23068672L; }
    else                    { src = dtw;    dst = WDT; off = 23592960L; }
    long j = i - off;
    float4 v = *reinterpret_cast<const float4*>(src + j);
    ushort2 a = {f2bf(v.x), f2bf(v.y)};
    ushort2 b = {f2bf(v.z), f2bf(v.w)};
    *reinterpret_cast<ushort2*>(dst + j)     = a;
    *reinterpret_cast<ushort2*>(dst + j + 2) = b;
}

// out = bf16(in + I), in is 2048x2048 row-major
__global__ void k_addI(const float* __restrict__ in, u16* __restrict__ out) {
    int i = (blockIdx.x * BDIM + threadIdx.x) * 4;
    int r = i >> 11, c = i & 2047;
    float4 v = *reinterpret_cast<const float4*>(in + i);
    if (r >= c && r < c + 4) (&v.x)[r - c] += 1.0f;
    ushort2 a = {f2bf(v.x), f2bf(v.y)};
    ushort2 b = {f2bf(v.z), f2bf(v.w)};
    *reinterpret_cast<ushort2*>(out + i)     = a;
    *reinterpret_cast<ushort2*>(out + i + 2) = b;
}

// ---------------------------------------------------------------------------
// GEMM: C[M x N] = A1[M x K1] * W1[N x K1]^T (+ A2[M x K2] * W2[N x K2]^T)
// bf16 in, f32 accumulate. LDS XOR-swizzle (r,c)->r*64+(c^((r&7)*8)).
// XCD-aware block swizzle: same-XCD blocks get contiguous m-major tile chunks.
// MODE 0: store bf16. MODE 2: store f32.
// MODE 5: log-decay: store bf16 of -exp(bias2[col])*softplus(v+bias1[col])
// ---------------------------------------------------------------------------
template <int MODE>
__global__ __launch_bounds__(256, 4)
void k_gemm(const u16* __restrict__ A1, const u16* __restrict__ W1, int K1,
            const u16* __restrict__ A2, const u16* __restrict__ W2, int K2,
            int N,
            float* __restrict__ outf, u16* __restrict__ outb,
            const float* __restrict__ bias1, const float* __restrict__ bias2) {
    __shared__ u16 As[128 * 64];
    __shared__ u16 Bs[128 * 64];
    const int tid  = threadIdx.x;
    const int wave = tid >> 6;
    const int lane = tid & 63;
    // XCD-aware tile remap (MI355X: 8 XCDs, blocks round-robin by linear id)
    int bid  = blockIdx.x + gridDim.x * blockIdx.y;
    int nloc = (gridDim.x * gridDim.y) >> 3;
    int nid  = (bid & 7) * nloc + (bid >> 3);
    const int m0 = (nid / gridDim.x) * 128;
    const int n0 = (nid % gridDim.x) * 128;
    const int wm = (wave >> 1) * 64;
    const int wn = (wave & 1) * 64;
    const int lr = lane & 15;
    const int lq = lane >> 4;
    const int stg_row = lane >> 3;                    // row within chunk (0..7)
    const int stg_col = (((lane & 7) ^ (lane >> 3)) << 3);

    f32x4 acc[4][4] = {};

    const int nt1 = K1 >> 6;
    const int nt2 = K2 >> 6;
    const int ntot = nt1 + nt2;

    for (int kt = 0; kt < ntot; ++kt) {
        const u16* Ap; const u16* Wp; int ld, k0;
        if (kt < nt1) { Ap = A1; Wp = W1; ld = K1; k0 = kt << 6; }
        else          { Ap = A2; Wp = W2; ld = K2; k0 = (kt - nt1) << 6; }
        #pragma unroll
        for (int i = 0; i < 4; ++i) {
            int chunk = wave * 4 + i;                 // 0..15 (wave-uniform)
            int r = chunk * 8 + stg_row;              // tile row this lane feeds
            load16_to_lds(Ap + (size_t)(m0 + r) * ld + (k0 + stg_col), As + chunk * 512);
            load16_to_lds(Wp + (size_t)(n0 + r) * ld + (k0 + stg_col), Bs + chunk * 512);
        }
        __syncthreads();
        #pragma unroll
        for (int kk = 0; kk < 64; kk += 32) {
            bf16x8 af[4], bfr[4];
            #pragma unroll
            for (int i = 0; i < 4; ++i) {
                int R = wm + i * 16 + lr;
                af[i] = *reinterpret_cast<const bf16x8*>(
                    &As[R * 64 + ((kk + lq * 8) ^ ((R & 7) << 3))]);
            }
            #pragma unroll
            for (int i = 0; i < 4; ++i) {
                int R = wn + i * 16 + lr;
                bfr[i] = *reinterpret_cast<const bf16x8*>(
                    &Bs[R * 64 + ((kk + lq * 8) ^ ((R & 7) << 3))]);
            }
            #pragma unroll
            for (int mi = 0; mi < 4; ++mi)
                #pragma unroll
                for (int ni = 0; ni < 4; ++ni)
                    acc[mi][ni] = __builtin_amdgcn_mfma_f32_16x16x32_bf16(
                        af[mi], bfr[ni], acc[mi][ni], 0, 0, 0);
        }
        __syncthreads();
    }

    #pragma unroll
    for (int mi = 0; mi < 4; ++mi) {
        #pragma unroll
        for (int ni = 0; ni < 4; ++ni) {
            #pragma unroll
            for (int j = 0; j < 4; ++j) {
                int row = m0 + wm + mi * 16 + lq * 4 + j;
                int col = n0 + wn + ni * 16 + lr;
                size_t idx = (size_t)row * N + col;
                float v = acc[mi][ni][j];
                if constexpr (MODE == 5) {
                    float dlt = v + bias1[col];
                    dlt = (dlt > 15.f) ? dlt : log1pf(expf(dlt));
                    v = -expf(bias2[col]) * dlt;          // log-decay
                }
                if constexpr (MODE == 2) outf[idx] = v;
                else                     outb[idx] = f2bf(v);
            }
        }
    }
}

// ---------------------------------------------------------------------------
// depthwise causal conv (k=4) + bias + SiLU over x[M_ROWS x DI]
// ---------------------------------------------------------------------------
__global__ void k_conv(const u16* __restrict__ x, const float* __restrict__ w,
                       const float* __restrict__ b, u16* __restrict__ out) {
    int idx = blockIdx.x * BDIM + threadIdx.x;   // over M_ROWS*DI
    int d  = idx & (DI - 1);
    int bl = idx >> 11;
    int l  = bl & (LSEQ - 1);
    float4 wv = *reinterpret_cast<const float4*>(w + d * 4);
    float wj[4] = {wv.x, wv.y, wv.z, wv.w};
    float acc = b[d];
    #pragma unroll
    for (int j = 0; j < 4; ++j) {
        int ll = l - 3 + j;
        if (ll >= 0) acc += wj[j] * bf2f(x[(size_t)(bl - 3 + j) * DI + d]);
    }
    out[idx] = f2bf(siluf(acc));
}

// ---------------------------------------------------------------------------
// cumsum over l (3-phase chunked): Bx bf16 -> states bf16 (fp32 accumulate)
// thread layout: t = ((b*NCH + c)*DI + s)
// ---------------------------------------------------------------------------
__global__ void k_cumsum_p1(const u16* __restrict__ Bx, float* __restrict__ aux) {
    int t = blockIdx.x * BDIM + threadIdx.x;
    int s = t & (DI - 1);
    int c = (t >> 11) & (NCH - 1);
    int b = t >> 17;
    const u16* p = Bx + ((size_t)(b * LSEQ + c * CLEN) * DI) + s;
    float sum = 0.f;
    for (int i = 0; i < CLEN; ++i) sum += bf2f(p[(size_t)i * DI]);
    aux[t] = sum;
}
__global__ void k_cumsum_p2(const float* __restrict__ aux, float* __restrict__ carry) {
    int t = blockIdx.x * BDIM + threadIdx.x;   // over B*DI
    int s = t & (DI - 1);
    int b = t >> 11;
    float run = 0.f;
    for (int c = 0; c < NCH; ++c) {
        int i = (b * NCH + c) * DI + s;
        carry[i] = run;
        run += aux[i];
    }
}
__global__ void k_cumsum_p3(const u16* __restrict__ Bx, const float* __restrict__ carry,
                            u16* __restrict__ st) {
    int t = blockIdx.x * BDIM + threadIdx.x;
    int s = t & (DI - 1);
    int c = (t >> 11) & (NCH - 1);
    int b = t >> 17;
    size_t base = ((size_t)(b * LSEQ + c * CLEN) * DI) + s;
    float run = carry[t];
    for (int i = 0; i < CLEN; ++i) {
        run += bf2f(Bx[base + (size_t)i * DI]);
        st[base + (size_t)i * DI] = f2bf(run);
    }
}

// ---------------------------------------------------------------------------
// selective scan (3-phase): s_l = a_l * s_{l-1} + u_l  with a = exp(logdec)
// p3 fuses: x4 = s + u*D_ss ; out = x4 * silu(z)
// ---------------------------------------------------------------------------
__global__ void k_scan_p1(const u16* __restrict__ ld_, const u16* __restrict__ u,
                          float* __restrict__ auxA, float* __restrict__ auxS) {
    int t = blockIdx.x * BDIM + threadIdx.x;
    int d = t & (DI - 1);
    int c = (t >> 11) & (NCH - 1);
    int b = t >> 17;
    size_t base = ((size_t)(b * LSEQ + c * CLEN) * DI) + d;
    float ap = 1.f, s = 0.f;
    for (int i = 0; i < CLEN; ++i) {
        size_t ix = base + (size_t)i * DI;
        float a = expf(bf2f(ld_[ix]));
        s = fmaf(a, s, bf2f(u[ix]));
        ap *= a;
    }
    auxA[t] = ap; auxS[t] = s;
}
__global__ void k_scan_p2(const float* __restrict__ auxA, const float* __restrict__ auxS,
                          float* __restrict__ carry) {
    int t = blockIdx.x * BDIM + threadIdx.x;   // over B*DI
    int d = t & (DI - 1);
    int b = t >> 11;
    float run = 0.f;
    for (int c = 0; c < NCH; ++c) {
        int i = (b * NCH + c) * DI + d;
        carry[i] = run;
        run = fmaf(auxA[i], run, auxS[i]);
    }
}
__global__ void k_scan_p3(const u16* __restrict__ ld_, const u16* __restrict__ u,
                          const float* __restrict__ carry, const u16* __restrict__ z,
                          const float* __restrict__ Dss, u16* __restrict__ outb) {
    int t = blockIdx.x * BDIM + threadIdx.x;
    int d = t & (DI - 1);
    int c = (t >> 11) & (NCH - 1);
    int b = t >> 17;
    size_t base = ((size_t)(b * LSEQ + c * CLEN) * DI) + d;
    float s = carry[t];
    float dss = Dss[d];
    for (int i = 0; i < CLEN; ++i) {
        size_t ix = base + (size_t)i * DI;
        float a = expf(bf2f(ld_[ix]));
        float uu = bf2f(u[ix]);
        s = fmaf(a, s, uu);
        float x4 = s + uu * dss;
        float zz = bf2f(z[ix]);
        outb[ix] = f2bf(x4 * siluf(zz));
    }
}

// ---------------------------------------------------------------------------
extern "C" void kernel_launch(void* const* d_in, const int* in_sizes, int n_in,
                              void* d_out, int out_size, void* d_ws, size_t ws_size,
                              hipStream_t stream) {
    const float* hs     = (const float*)d_in[0];
    const float* delta  = (const float*)d_in[1];
    const float* inproj = (const float*)d_in[2];
    const float* convw  = (const float*)d_in[3];
    const float* convb  = (const float*)d_in[4];
    const float* Areal  = (const float*)d_in[5];
    const float* Bw     = (const float*)d_in[6];
    const float* Cw     = (const float*)d_in[7];
    const float* Dw     = (const float*)d_in[8];
    const float* dtw    = (const float*)d_in[9];
    const float* dtb    = (const float*)d_in[10];
    const float* Alog   = (const float*)d_in[11];
    const float* Dss    = (const float*)d_in[12];
    const float* outw   = (const float*)d_in[13];
    float* out = (float*)d_out;

    // ---- liveness-overlaid workspace layout (~239 MB total) ----
    const size_t SZ_ACT = (size_t)M_ROWS * DI * 2;     // 32 MB
    char* p = (char*)d_ws;
    u16* ZB  = (u16*)p; p += SZ_ACT;                   // z: G1 -> scan_p3
    u16* XB  = (u16*)p;                                // x: G1 -> conv
    u16* X3  = XB;      p += SZ_ACT;                   // X3: G45' -> scan_p3
    u16* XC  = (u16*)p;                                // conv out -> G3',G45'
    u16* OUT = XC;      p += SZ_ACT;                   // scan_p3 out -> G7
    u16* BX  = (u16*)p;                                // G3' out -> cumsum
    u16* LD  = BX;      p += SZ_ACT;                   // log-decay: G6 -> scan
    u16* ST  = (u16*)p; p += SZ_ACT;                   // states: cumsum -> G45'
    u16* XH  = (u16*)p; p += (size_t)M_ROWS * 1024 * 2;   // 16 MB
    u16* W1  = (u16*)p; p += (size_t)4096 * 1024 * 2;     // 8 MB
    u16* WBb = (u16*)p; p += (size_t)DI * DI * 2;         // 8 MB  bf16(B_w)
    u16* WC  = (u16*)p; p += (size_t)DI * DI * 2;         // 8 MB  bf16(C_w)
    u16* Pb  = (u16*)p; p += (size_t)DI * DI * 2;         // 8 MB  bf16(I+A_real)
    u16* Db  = (u16*)p; p += (size_t)DI * DI * 2;         // 8 MB  bf16(I+D_w)
    u16* WBp = (u16*)p; p += (size_t)DI * DI * 2;         // 8 MB  B_w @ P^T
    u16* WXp = (u16*)p; p += (size_t)DI * DI * 2;         // 8 MB  (I+D_w) @ P^T
    u16* WO  = (u16*)p; p += (size_t)1024 * DI * 2;       // 4 MB
    u16* WDT = (u16*)p; p += (size_t)DI * 64 * 2;
    u16* DLT = (u16*)p; p += (size_t)M_ROWS * 64 * 2;
    float* aux1 = (float*)p; p += (size_t)2 * NCH * DI * 4;
    float* aux2 = (float*)p; p += (size_t)2 * NCH * DI * 4;
    float* auxA = (float*)p; p += (size_t)2 * NCH * DI * 4;
    float* auxS = (float*)p; p += (size_t)2 * NCH * DI * 4;
    float* auxC = (float*)p; p += (size_t)2 * NCH * DI * 4;

    // ---- converts (3 launches) ----
    k_cvt_all<<<23168, BDIM, 0, stream>>>(hs, inproj, Bw, Cw, outw, delta, dtw,
                                          XH, W1, WBb, WC, WO, DLT, WDT);
    k_addI<<<4096, BDIM, 0, stream>>>(Areal, Pb);
    k_addI<<<4096, BDIM, 0, stream>>>(Dw, Db);

    // ---- folded-weight precomputes: WBp = WBb @ Pb^T ; WXp = Db @ Pb^T ----
    k_gemm<0><<<dim3(16, 16), BDIM, 0, stream>>>(WBb, Pb, DI, nullptr, nullptr, 0,
                                                 DI, nullptr, WBp, nullptr, nullptr);
    k_gemm<0><<<dim3(16, 16), BDIM, 0, stream>>>(Db, Pb, DI, nullptr, nullptr, 0,
                                                 DI, nullptr, WXp, nullptr, nullptr);

    // ---- G1: x = hs @ in_proj[0:2048]^T ; z = hs @ in_proj[2048:4096]^T ----
    k_gemm<0><<<dim3(16, 64), BDIM, 0, stream>>>(XH, W1, 1024, nullptr, nullptr, 0,
                                                 DI, nullptr, XB, nullptr, nullptr);
    k_gemm<0><<<dim3(16, 64), BDIM, 0, stream>>>(XH, W1 + (size_t)DI * 1024, 1024,
                                                 nullptr, nullptr, 0,
                                                 DI, nullptr, ZB, nullptr, nullptr);
    // ---- conv + SiLU ----
    k_conv<<<(M_ROWS * DI) / BDIM, BDIM, 0, stream>>>(XB, convw, convb, XC);
    // ---- G3': BX = XC @ WBp^T  (folded: == X2 @ B_w^T) ----
    k_gemm<0><<<dim3(16, 64), BDIM, 0, stream>>>(XC, WBp, DI, nullptr, nullptr, 0,
                                                 DI, nullptr, BX, nullptr, nullptr);
    // ---- cumsum -> states ----
    k_cumsum_p1<<<(2 * NCH * DI) / BDIM, BDIM, 0, stream>>>(BX, aux1);
    k_cumsum_p2<<<(2 * DI) / BDIM, BDIM, 0, stream>>>(aux1, aux2);
    k_cumsum_p3<<<(2 * NCH * DI) / BDIM, BDIM, 0, stream>>>(BX, aux2, ST);
    // ---- G6: LD = -exp(A_log) * softplus(delta @ dt_proj^T + dt_b) ----
    k_gemm<5><<<dim3(16, 64), BDIM, 0, stream>>>(DLT, WDT, 64, nullptr, nullptr, 0,
                                                 DI, nullptr, LD, dtb, Alog);
    // ---- G45': X3 = ST @ WC^T + XC @ WXp^T  (folded: == X2 + ST@C^T + X2@D^T) ----
    k_gemm<0><<<dim3(16, 64), BDIM, 0, stream>>>(ST, WC, DI, XC, WXp, DI,
                                                 DI, nullptr, X3, nullptr, nullptr);
    // ---- selective scan + fused epilogue -> OUT (overlays dead XC) ----
    k_scan_p1<<<(2 * NCH * DI) / BDIM, BDIM, 0, stream>>>(LD, X3, auxA, auxS);
    k_scan_p2<<<(2 * DI) / BDIM, BDIM, 0, stream>>>(auxA, auxS, auxC);
    k_scan_p3<<<(2 * NCH * DI) / BDIM, BDIM, 0, stream>>>(LD, X3, auxC, ZB, Dss, OUT);
    // ---- G7: out = OUT @ out_proj^T (M=8192, N=1024, K=2048, f32 out) ----
    k_gemm<2><<<dim3(8, 64), BDIM, 0, stream>>>(OUT, WO, DI, nullptr, nullptr, 0,
                                                1024, out, nullptr, nullptr, nullptr);
}

// Round 6
// 703.870 us; speedup vs baseline: 1.1960x; 1.0560x over previous
//
#include <hip/hip_runtime.h>
#include <cstdint>
#include <cstddef>

// ---------------------------------------------------------------------------
// Mamba3Block on MI355X. B=2, L=4096, D_MODEL=1024, D_INNER=D_STATE=2048.
// R6: launch-count attack (18 -> 10 dispatches):
//  - addI folded into cvt_all; pre1+pre2+G1(split N=4096) in one dispatch;
//  - G3'+G6 in one dispatch (LD overlays dead XH+W1+WBb = exactly 32 MB);
//  - cumsum/scan 3 -> 2 kernels (p2 folded into p3).
// GEMM core: bf16 MFMA 16x16x32, 128x128 tile, BK=64, global_load_lds w16,
// XOR-swizzled LDS (conflicts = 0), XCD-aware tile remap. Scans fp32 with
// bf16 log-decay storage (conditioning: store exponent, not decay).
// ---------------------------------------------------------------------------

typedef unsigned short u16;                 // bf16 storage (bit pattern)
typedef __bf16 bf16x8 __attribute__((ext_vector_type(8)));
typedef float  f32x4  __attribute__((ext_vector_type(4)));

#define BDIM 256
#define M_ROWS 8192            // B*L
#define LSEQ   4096
#define DI     2048            // d_inner / d_state
#define NCH    64              // scan chunks
#define CLEN   64              // LSEQ / NCH

__device__ __forceinline__ float bf2f(u16 h) {
    return __uint_as_float(((unsigned int)h) << 16);
}
__device__ __forceinline__ u16 f2bf(float f) {
    unsigned int u = __float_as_uint(f);
    u = u + 0x7fffu + ((u >> 16) & 1u);     // RNE
    return (u16)(u >> 16);
}
__device__ __forceinline__ float siluf(float v) { return v / (1.0f + expf(-v)); }

__device__ __forceinline__ void load16_to_lds(const u16* g, u16* l) {
    __builtin_amdgcn_global_load_lds((const __attribute__((address_space(1))) void*)g,
                                     (__attribute__((address_space(3))) void*)l,
                                     16, 0, 0);
}

// ---------------------------------------------------------------------------
// fused f32 -> bf16 convert of ALL inputs (1 launch), incl. +I diag segments.
// element boundaries (all div by 4):
// hs 8388608 | inproj 12582912 | Bw 16777216 | Cw 20971520 | outw 23068672 |
// delta 23592960 | dtw 23724032 | Areal(+I) 27918336 | Dw(+I) 32112640
// ---------------------------------------------------------------------------
__global__ void k_cvt_all(const float* __restrict__ hs, const float* __restrict__ inproj,
                          const float* __restrict__ Bw, const float* __restrict__ Cw,
                          const float* __restrict__ outw, const float* __restrict__ delta,
                          const float* __restrict__ dtw, const float* __restrict__ Areal,
                          const float* __restrict__ Dw,
                          u16* __restrict__ XH, u16* __restrict__ W1, u16* __restrict__ WBb,
                          u16* __restrict__ WC, u16* __restrict__ WO, u16* __restrict__ DLT,
                          u16* __restrict__ WDT, u16* __restrict__ Pb, u16* __restrict__ Db) {
    long i = (long)(blockIdx.x * BDIM + threadIdx.x) * 4;
    const float* src; u16* dst; long off; bool diag = false;
    if      (i <  8388608L) { src = hs;     dst = XH;  off = 0L; }
    else if (i < 12582912L) { src = inproj; dst = W1;  off = 8388608L; }
    else if (i < 16777216L) { src = Bw;     dst = WBb; off = 12582912L; }
    else if (i < 20971520L) { src = Cw;     dst = WC;  off = 16777216L; }
    else if (i < 23068672L) { src = outw;   dst = WO;  off = 20971520L; }
    else if (i < 23592960L) { src = delta;  dst = DLT; off = 23068672L; }
    else if (i < 23724032L) { src = dtw;    dst = WDT; off = 23592960L; }
    else if (i < 27918336L) { src = Areal;  dst = Pb;  off = 23724032L; diag = true; }
    else                    { src = Dw;     dst = Db;  off = 27918336L; diag = true; }
    long j = i - off;
    float4 v = *reinterpret_cast<const float4*>(src + j);
    if (diag) {
        int r = (int)(j >> 11), c = (int)(j & 2047);
        if (r >= c && r < c + 4) (&v.x)[r - c] += 1.0f;
    }
    ushort2 a = {f2bf(v.x), f2bf(v.y)};
    ushort2 b = {f2bf(v.z), f2bf(v.w)};
    *reinterpret_cast<ushort2*>(dst + j)     = a;
    *reinterpret_cast<ushort2*>(dst + j + 2) = b;
}

// ---------------------------------------------------------------------------
// GEMM tile core: C_tile = A1*W1^T (+ A2*W2^T), bf16 in, f32 acc.
// LDS XOR-swizzle (r,c) -> r*64 + (c ^ ((r&7)*8)); staging = global_load_lds.
// mode 0: store bf16[N-stride]; 2: store f32; 5: log-decay bf16;
// 6: split store (col<2048 -> outb, else outb2, both stride 2048)
// ---------------------------------------------------------------------------
__device__ __forceinline__ void gemm_core(
    u16* As, u16* Bs,
    const u16* __restrict__ A1, const u16* __restrict__ W1, int K1,
    const u16* __restrict__ A2, const u16* __restrict__ W2, int K2,
    int N, float* __restrict__ outf, u16* __restrict__ outb, u16* __restrict__ outb2,
    const float* __restrict__ bias1, const float* __restrict__ bias2,
    int m0, int n0, int mode) {
    const int tid  = threadIdx.x;
    const int wave = tid >> 6;
    const int lane = tid & 63;
    const int wm = (wave >> 1) * 64;
    const int wn = (wave & 1) * 64;
    const int lr = lane & 15;
    const int lq = lane >> 4;
    const int stg_row = lane >> 3;
    const int stg_col = (((lane & 7) ^ (lane >> 3)) << 3);

    f32x4 acc[4][4] = {};

    const int nt1 = K1 >> 6;
    const int nt2 = K2 >> 6;
    const int ntot = nt1 + nt2;

    for (int kt = 0; kt < ntot; ++kt) {
        const u16* Ap; const u16* Wp; int ld, k0;
        if (kt < nt1) { Ap = A1; Wp = W1; ld = K1; k0 = kt << 6; }
        else          { Ap = A2; Wp = W2; ld = K2; k0 = (kt - nt1) << 6; }
        #pragma unroll
        for (int i = 0; i < 4; ++i) {
            int chunk = wave * 4 + i;                 // wave-uniform
            int r = chunk * 8 + stg_row;
            load16_to_lds(Ap + (size_t)(m0 + r) * ld + (k0 + stg_col), As + chunk * 512);
            load16_to_lds(Wp + (size_t)(n0 + r) * ld + (k0 + stg_col), Bs + chunk * 512);
        }
        __syncthreads();
        #pragma unroll
        for (int kk = 0; kk < 64; kk += 32) {
            bf16x8 af[4], bfr[4];
            #pragma unroll
            for (int i = 0; i < 4; ++i) {
                int R = wm + i * 16 + lr;
                af[i] = *reinterpret_cast<const bf16x8*>(
                    &As[R * 64 + ((kk + lq * 8) ^ ((R & 7) << 3))]);
            }
            #pragma unroll
            for (int i = 0; i < 4; ++i) {
                int R = wn + i * 16 + lr;
                bfr[i] = *reinterpret_cast<const bf16x8*>(
                    &Bs[R * 64 + ((kk + lq * 8) ^ ((R & 7) << 3))]);
            }
            #pragma unroll
            for (int mi = 0; mi < 4; ++mi)
                #pragma unroll
                for (int ni = 0; ni < 4; ++ni)
                    acc[mi][ni] = __builtin_amdgcn_mfma_f32_16x16x32_bf16(
                        af[mi], bfr[ni], acc[mi][ni], 0, 0, 0);
        }
        __syncthreads();
    }

    #pragma unroll
    for (int mi = 0; mi < 4; ++mi) {
        #pragma unroll
        for (int ni = 0; ni < 4; ++ni) {
            #pragma unroll
            for (int j = 0; j < 4; ++j) {
                int row = m0 + wm + mi * 16 + lq * 4 + j;
                int col = n0 + wn + ni * 16 + lr;
                float v = acc[mi][ni][j];
                if (mode == 6) {
                    if (col < 2048) outb [(size_t)row * 2048 + col]        = f2bf(v);
                    else            outb2[(size_t)row * 2048 + col - 2048] = f2bf(v);
                } else if (mode == 5) {
                    float dlt = v + bias1[col];
                    dlt = (dlt > 15.f) ? dlt : log1pf(expf(dlt));
                    outb[(size_t)row * N + col] = f2bf(-expf(bias2[col]) * dlt);
                } else if (mode == 2) {
                    outf[(size_t)row * N + col] = v;
                } else {
                    outb[(size_t)row * N + col] = f2bf(v);
                }
            }
        }
    }
}

// XCD-aware remap within a sub-grid of T tiles (T divisible by 8), gn n-tiles
__device__ __forceinline__ void tile_coords(int q, int T, int gn, int& m0, int& n0) {
    int nloc = T >> 3;
    int nid  = (q & 7) * nloc + (q >> 3);
    m0 = (nid / gn) * 128;
    n0 = (nid % gn) * 128;
}

// batch1: [0,256) pre1 WBp=WBb@Pb^T | [256,512) pre2 WXp=Db@Pb^T |
//         [512,2560) G1 split: XZ = XH @ W1^T (N=4096) -> XB / ZB
__global__ __launch_bounds__(256, 4)
void k_batch1(const u16* __restrict__ XH, const u16* __restrict__ W1,
              const u16* __restrict__ WBb, const u16* __restrict__ Pb,
              const u16* __restrict__ Db,
              u16* __restrict__ WBp, u16* __restrict__ WXp,
              u16* __restrict__ XB, u16* __restrict__ ZB) {
    __shared__ u16 As[128 * 64];
    __shared__ u16 Bs[128 * 64];
    int bid = blockIdx.x;
    int m0, n0;
    if (bid < 256) {
        tile_coords(bid, 256, 16, m0, n0);
        gemm_core(As, Bs, WBb, Pb, DI, nullptr, nullptr, 0, DI,
                  nullptr, WBp, nullptr, nullptr, nullptr, m0, n0, 0);
    } else if (bid < 512) {
        tile_coords(bid - 256, 256, 16, m0, n0);
        gemm_core(As, Bs, Db, Pb, DI, nullptr, nullptr, 0, DI,
                  nullptr, WXp, nullptr, nullptr, nullptr, m0, n0, 0);
    } else {
        tile_coords(bid - 512, 2048, 32, m0, n0);
        gemm_core(As, Bs, XH, W1, 1024, nullptr, nullptr, 0, 4096,
                  nullptr, XB, ZB, nullptr, nullptr, m0, n0, 6);
    }
}

// batch2: [0,1024) G3' BX = XC@WBp^T | [1024,2048) G6 LD = logdecay(DLT@WDT^T)
__global__ __launch_bounds__(256, 4)
void k_batch2(const u16* __restrict__ XC, const u16* __restrict__ WBp,
              const u16* __restrict__ DLT, const u16* __restrict__ WDT,
              const float* __restrict__ dtb, const float* __restrict__ Alog,
              u16* __restrict__ BX, u16* __restrict__ LD) {
    __shared__ u16 As[128 * 64];
    __shared__ u16 Bs[128 * 64];
    int bid = blockIdx.x;
    int m0, n0;
    if (bid < 1024) {
        tile_coords(bid, 1024, 16, m0, n0);
        gemm_core(As, Bs, XC, WBp, DI, nullptr, nullptr, 0, DI,
                  nullptr, BX, nullptr, nullptr, nullptr, m0, n0, 0);
    } else {
        tile_coords(bid - 1024, 1024, 16, m0, n0);
        gemm_core(As, Bs, DLT, WDT, 64, nullptr, nullptr, 0, DI,
                  nullptr, LD, nullptr, dtb, Alog, m0, n0, 5);
    }
}

// single GEMM wrapper (G45', G7)
template <int MODE>
__global__ __launch_bounds__(256, 4)
void k_gemm(const u16* __restrict__ A1, const u16* __restrict__ W1, int K1,
            const u16* __restrict__ A2, const u16* __restrict__ W2, int K2,
            int N, float* __restrict__ outf, u16* __restrict__ outb) {
    __shared__ u16 As[128 * 64];
    __shared__ u16 Bs[128 * 64];
    int bid = blockIdx.x + gridDim.x * blockIdx.y;
    int m0, n0;
    tile_coords(bid, gridDim.x * gridDim.y, gridDim.x, m0, n0);
    gemm_core(As, Bs, A1, W1, K1, A2, W2, K2, N,
              outf, outb, nullptr, nullptr, nullptr, m0, n0, MODE);
}

// ---------------------------------------------------------------------------
// depthwise causal conv (k=4) + bias + SiLU over x[M_ROWS x DI]
// ---------------------------------------------------------------------------
__global__ void k_conv(const u16* __restrict__ x, const float* __restrict__ w,
                       const float* __restrict__ b, u16* __restrict__ out) {
    int idx = blockIdx.x * BDIM + threadIdx.x;   // over M_ROWS*DI
    int d  = idx & (DI - 1);
    int bl = idx >> 11;
    int l  = bl & (LSEQ - 1);
    float4 wv = *reinterpret_cast<const float4*>(w + d * 4);
    float wj[4] = {wv.x, wv.y, wv.z, wv.w};
    float acc = b[d];
    #pragma unroll
    for (int j = 0; j < 4; ++j) {
        int ll = l - 3 + j;
        if (ll >= 0) acc += wj[j] * bf2f(x[(size_t)(bl - 3 + j) * DI + d]);
    }
    out[idx] = f2bf(siluf(acc));
}

// ---------------------------------------------------------------------------
// cumsum over l (2-kernel chunked): Bx bf16 -> states bf16 (fp32 accumulate)
// thread layout: t = ((b*NCH + c)*DI + s); NCH*DI = 2^17
// ---------------------------------------------------------------------------
__global__ void k_cumsum_p1(const u16* __restrict__ Bx, float* __restrict__ aux) {
    int t = blockIdx.x * BDIM + threadIdx.x;
    int s = t & (DI - 1);
    int c = (t >> 11) & (NCH - 1);
    int b = t >> 17;
    const u16* p = Bx + ((size_t)(b * LSEQ + c * CLEN) * DI) + s;
    float sum = 0.f;
    for (int i = 0; i < CLEN; ++i) sum += bf2f(p[(size_t)i * DI]);
    aux[t] = sum;
}
__global__ void k_cumsum_p23(const u16* __restrict__ Bx, const float* __restrict__ aux,
                             u16* __restrict__ st) {
    int t = blockIdx.x * BDIM + threadIdx.x;
    int s = t & (DI - 1);
    int c = (t >> 11) & (NCH - 1);
    int b = t >> 17;
    float run = 0.f;
    for (int j = 0; j < c; ++j) run += aux[(b * NCH + j) * DI + s];   // fold p2
    size_t base = ((size_t)(b * LSEQ + c * CLEN) * DI) + s;
    for (int i = 0; i < CLEN; ++i) {
        run += bf2f(Bx[base + (size_t)i * DI]);
        st[base + (size_t)i * DI] = f2bf(run);
    }
}

// ---------------------------------------------------------------------------
// selective scan (2-kernel): s_l = a_l * s_{l-1} + u_l with a = exp(logdec)
// p23 fuses carry fold + x4 = s + u*D_ss ; out = x4 * silu(z)
// ---------------------------------------------------------------------------
__global__ void k_scan_p1(const u16* __restrict__ ld_, const u16* __restrict__ u,
                          float* __restrict__ auxA, float* __restrict__ auxS) {
    int t = blockIdx.x * BDIM + threadIdx.x;
    int d = t & (DI - 1);
    int c = (t >> 11) & (NCH - 1);
    int b = t >> 17;
    size_t base = ((size_t)(b * LSEQ + c * CLEN) * DI) + d;
    float ap = 1.f, s = 0.f;
    for (int i = 0; i < CLEN; ++i) {
        size_t ix = base + (size_t)i * DI;
        float a = expf(bf2f(ld_[ix]));
        s = fmaf(a, s, bf2f(u[ix]));
        ap *= a;
    }
    auxA[t] = ap; auxS[t] = s;
}
__global__ void k_scan_p23(const u16* __restrict__ ld_, const u16* __restrict__ u,
                           const float* __restrict__ auxA, const float* __restrict__ auxS,
                           const u16* __restrict__ z, const float* __restrict__ Dss,
                           u16* __restrict__ outb) {
    int t = blockIdx.x * BDIM + threadIdx.x;
    int d = t & (DI - 1);
    int c = (t >> 11) & (NCH - 1);
    int b = t >> 17;
    float s = 0.f;
    for (int j = 0; j < c; ++j) {                                    // fold p2
        int i = (b * NCH + j) * DI + d;
        s = fmaf(auxA[i], s, auxS[i]);
    }
    size_t base = ((size_t)(b * LSEQ + c * CLEN) * DI) + d;
    float dss = Dss[d];
    for (int i = 0; i < CLEN; ++i) {
        size_t ix = base + (size_t)i * DI;
        float a = expf(bf2f(ld_[ix]));
        float uu = bf2f(u[ix]);
        s = fmaf(a, s, uu);
        float x4 = s + uu * dss;
        float zz = bf2f(z[ix]);
        outb[ix] = f2bf(x4 * siluf(zz));
    }
}

// ---------------------------------------------------------------------------
extern "C" void kernel_launch(void* const* d_in, const int* in_sizes, int n_in,
                              void* d_out, int out_size, void* d_ws, size_t ws_size,
                              hipStream_t stream) {
    const float* hs     = (const float*)d_in[0];
    const float* delta  = (const float*)d_in[1];
    const float* inproj = (const float*)d_in[2];
    const float* convw  = (const float*)d_in[3];
    const float* convb  = (const float*)d_in[4];
    const float* Areal  = (const float*)d_in[5];
    const float* Bw     = (const float*)d_in[6];
    const float* Cw     = (const float*)d_in[7];
    const float* Dw     = (const float*)d_in[8];
    const float* dtw    = (const float*)d_in[9];
    const float* dtb    = (const float*)d_in[10];
    const float* Alog   = (const float*)d_in[11];
    const float* Dss    = (const float*)d_in[12];
    const float* outw   = (const float*)d_in[13];
    float* out = (float*)d_out;

    // ---- liveness-overlaid workspace layout (~241 MB total) ----
    const size_t SZ_ACT = (size_t)M_ROWS * DI * 2;     // 32 MB
    char* p = (char*)d_ws;
    u16* ZB  = (u16*)p; p += SZ_ACT;                   // z: batch1 -> scan_p23
    u16* XB  = (u16*)p;                                // x: batch1 -> conv
    u16* X3  = XB;      p += SZ_ACT;                   // X3: G45' -> scans
    u16* XC  = (u16*)p;                                // conv out -> batch2,G45'
    u16* OUT = XC;      p += SZ_ACT;                   // scan_p23 out -> G7
    u16* BX  = (u16*)p; p += SZ_ACT;                   // batch2 out -> cumsum
    u16* ST  = (u16*)p; p += SZ_ACT;                   // states: cumsum -> G45'
    u16* XH  = (u16*)p;                                // hs bf16 (dead after batch1)
    u16* LD  = XH;                                     // log-decay overlays XH+W1+WBb (32MB)
                        p += (size_t)M_ROWS * 1024 * 2;   // 16 MB
    u16* W1  = (u16*)p; p += (size_t)4096 * 1024 * 2;     // 8 MB
    u16* WBb = (u16*)p; p += (size_t)DI * DI * 2;         // 8 MB  bf16(B_w)
    u16* WC  = (u16*)p; p += (size_t)DI * DI * 2;         // 8 MB  bf16(C_w)
    u16* Pb  = (u16*)p; p += (size_t)DI * DI * 2;         // 8 MB  bf16(I+A_real)
    u16* Db  = (u16*)p; p += (size_t)DI * DI * 2;         // 8 MB  bf16(I+D_w)
    u16* WBp = (u16*)p; p += (size_t)DI * DI * 2;         // 8 MB  B_w @ P^T
    u16* WXp = (u16*)p; p += (size_t)DI * DI * 2;         // 8 MB  (I+D_w) @ P^T
    u16* WO  = (u16*)p; p += (size_t)1024 * DI * 2;       // 4 MB
    u16* WDT = (u16*)p; p += (size_t)DI * 64 * 2;
    u16* DLT = (u16*)p; p += (size_t)M_ROWS * 64 * 2;
    float* aux1 = (float*)p; p += (size_t)2 * NCH * DI * 4;   // 1 MB
    float* auxA = (float*)p; p += (size_t)2 * NCH * DI * 4;
    float* auxS = (float*)p; p += (size_t)2 * NCH * DI * 4;

    // 1) all converts (incl. +I for Pb/Db)
    k_cvt_all<<<31360, BDIM, 0, stream>>>(hs, inproj, Bw, Cw, outw, delta, dtw,
                                          Areal, Dw,
                                          XH, W1, WBb, WC, WO, DLT, WDT, Pb, Db);
    // 2) pre1 + pre2 + G1(split)
    k_batch1<<<2560, BDIM, 0, stream>>>(XH, W1, WBb, Pb, Db, WBp, WXp, XB, ZB);
    // 3) conv + SiLU
    k_conv<<<(M_ROWS * DI) / BDIM, BDIM, 0, stream>>>(XB, convw, convb, XC);
    // 4) G3' (BX) + G6 (LD, overlays dead XH/W1/WBb)
    k_batch2<<<2048, BDIM, 0, stream>>>(XC, WBp, DLT, WDT, dtb, Alog, BX, LD);
    // 5-6) cumsum -> ST
    k_cumsum_p1<<<(2 * NCH * DI) / BDIM, BDIM, 0, stream>>>(BX, aux1);
    k_cumsum_p23<<<(2 * NCH * DI) / BDIM, BDIM, 0, stream>>>(BX, aux1, ST);
    // 7) G45': X3 = ST@WC^T + XC@WXp^T
    k_gemm<0><<<dim3(16, 64), BDIM, 0, stream>>>(ST, WC, DI, XC, WXp, DI,
                                                 DI, nullptr, X3);
    // 8-9) selective scan + epilogue -> OUT (overlays dead XC)
    k_scan_p1<<<(2 * NCH * DI) / BDIM, BDIM, 0, stream>>>(LD, X3, auxA, auxS);
    k_scan_p23<<<(2 * NCH * DI) / BDIM, BDIM, 0, stream>>>(LD, X3, auxA, auxS,
                                                           ZB, Dss, OUT);
    // 10) G7: out = OUT @ out_proj^T (f32)
    k_gemm<2><<<dim3(8, 64), BDIM, 0, stream>>>(OUT, WO, DI, nullptr, nullptr, 0,
                                                1024, out, nullptr);
}